// Round 12
// baseline (95.811 us; speedup 1.0000x reference)
//
#include <hip/hip_runtime.h>
#include <hip/hip_bf16.h>
#include <math.h>

#define B_ 2
#define T_ 2048
#define D_ 512
#define H_ 16
#define DH 32
#define L_ 64
#define C_ 32
#define NC 1024    // total chunks
#define VTP 72     // LDS row stride (ushorts) for chunk kernels
#define CSZ 1056   // floats per chunk state tile (33 rows x 32)

typedef __attribute__((ext_vector_type(8))) short bf16x8;
typedef __attribute__((ext_vector_type(4))) float f32x4;
typedef __attribute__((ext_vector_type(4))) unsigned short u16x4;

#define AS1 __attribute__((address_space(1)))
#define AS3 __attribute__((address_space(3)))

__device__ __forceinline__ float bf2f(unsigned short u) {
    union { float f; unsigned int i; } v; v.i = ((unsigned int)u) << 16; return v.f;
}
__device__ __forceinline__ unsigned short f2bf(float f) {
    union { float f; unsigned int u; } v; v.f = f;
    unsigned int u = v.u;
    unsigned int r = u + 0x7FFFu + ((u >> 16) & 1u);
    return (unsigned short)(r >> 16);
}
// compiler-visible RNE conversion (lets hipcc emit v_cvt_pk_bf16_f32 for pairs)
__device__ __forceinline__ unsigned short f2bf_rne(float f) {
    __hip_bfloat16 h = __float2bfloat16(f);
    union { __hip_bfloat16 h; unsigned short u; } v; v.h = h; return v.u;
}
__device__ __forceinline__ bf16x8 phi_frag(bf16x8 in) {
    bf16x8 r;
    #pragma unroll
    for (int i = 0; i < 8; ++i) {
        float f = bf2f((unsigned short)in[i]);
        f = f > 0.f ? f + 1.f : __expf(f);
        r[i] = (short)f2bf(f);
    }
    return r;
}
__device__ __forceinline__ void gload_lds16(const unsigned short* g, unsigned short* l) {
    __builtin_amdgcn_global_load_lds((const AS1 unsigned int*)g, (AS3 unsigned int*)l, 16, 0, 0);
}

// C[m][n] = sum_k A[m][k]*W[n][k]; BMx128 tile, 4 waves (2x2), 16x16x32 bf16 MFMA.
// W is always fp32, converted during reg-staging (T14: load early, cvt+ds_write late).
// A is fp32 (reg-staged convert) when AF32, else bf16 via async global_load_lds.
template<int BM, bool AF32, bool OUT_BF16>
__global__ __launch_bounds__(256) void gemm_nt(const void* __restrict__ Aptr,
                                               const float* __restrict__ Wf,
                                               void* __restrict__ Cout,
                                               int N, int K)
{
    constexpr int MF = BM / 32;        // m-fragments per wave
    constexpr int AF4 = BM / 32;       // float4 loads per lane for fp32 A staging
    __shared__ unsigned short As[2][BM][32];
    __shared__ unsigned short Bs[2][128][32];
    const int tid = threadIdx.x;
    const int lane = tid & 63;
    const int wave = tid >> 6;
    const int wr = wave >> 1;
    const int wc = wave & 1;
    const size_t bm = (size_t)blockIdx.x * BM;
    const size_t bn = (size_t)blockIdx.y * 128;

    const int r8 = lane >> 3;          // 0..7 (f32 staging row-in-group)
    const int c4 = (lane & 7) * 4;     // f32 staging col (floats)
    const int lrow = lane >> 2;        // bf16 gload row
    const int lcol = (lane & 3) * 8;   // bf16 gload col

    const float* agf = nullptr;
    const unsigned short* agb = nullptr;
    if constexpr (AF32) agf = (const float*)Aptr + (bm + wave * (BM / 4) + r8) * (size_t)K + c4;
    else                agb = (const unsigned short*)Aptr + (bm + wave * (BM / 4) + lrow) * (size_t)K + lcol;
    const float* wgf = Wf + (bn + wave * 32 + r8) * (size_t)K + c4;

    f32x4 aL[AF4];
    f32x4 wL[4];

    auto load_stage = [&](int buf, int k0) {
        if constexpr (AF32) {
            #pragma unroll
            for (int i = 0; i < AF4; ++i)
                aL[i] = *(const f32x4*)(agf + k0 + (size_t)(i * 8) * K);
        } else {
            gload_lds16(agb + k0, &As[buf][wave * (BM / 4)][0]);
            if constexpr (BM / 4 == 32)
                gload_lds16(agb + (size_t)16 * K + k0, &As[buf][wave * (BM / 4) + 16][0]);
        }
        #pragma unroll
        for (int i = 0; i < 4; ++i)
            wL[i] = *(const f32x4*)(wgf + k0 + (size_t)(i * 8) * K);
    };
    auto write_stage = [&](int buf) {
        if constexpr (AF32) {
            #pragma unroll
            for (int i = 0; i < AF4; ++i) {
                u16x4 o;
                o.x = f2bf_rne(aL[i][0]); o.y = f2bf_rne(aL[i][1]);
                o.z = f2bf_rne(aL[i][2]); o.w = f2bf_rne(aL[i][3]);
                *(u16x4*)&As[buf][wave * (BM / 4) + r8 + i * 8][c4] = o;
            }
        }
        #pragma unroll
        for (int i = 0; i < 4; ++i) {
            u16x4 o;
            o.x = f2bf_rne(wL[i][0]); o.y = f2bf_rne(wL[i][1]);
            o.z = f2bf_rne(wL[i][2]); o.w = f2bf_rne(wL[i][3]);
            *(u16x4*)&Bs[buf][wave * 32 + r8 + i * 8][c4] = o;
        }
    };

    f32x4 acc[MF][4];
    #pragma unroll
    for (int m = 0; m < MF; ++m)
        #pragma unroll
        for (int n = 0; n < 4; ++n)
            acc[m][n] = (f32x4){0.f, 0.f, 0.f, 0.f};

    const int rr = lane & 15;
    const int kb = (lane >> 4) * 8;

    load_stage(0, 0);
    write_stage(0);
    __syncthreads();
    int cur = 0;
    for (int k0 = 0; k0 < K; k0 += 32) {
        const bool more = k0 + 32 < K;
        if (more) load_stage(cur ^ 1, k0 + 32);   // issue loads early (latency under MFMA)
        bf16x8 af[MF], bfr[4];
        #pragma unroll
        for (int m = 0; m < MF; ++m)
            af[m] = *(const bf16x8*)&As[cur][wr * (BM / 2) + m * 16 + rr][kb];
        #pragma unroll
        for (int n = 0; n < 4; ++n)
            bfr[n] = *(const bf16x8*)&Bs[cur][wc * 64 + n * 16 + rr][kb];
        #pragma unroll
        for (int m = 0; m < MF; ++m)
            #pragma unroll
            for (int n = 0; n < 4; ++n)
                acc[m][n] = __builtin_amdgcn_mfma_f32_16x16x32_bf16(af[m], bfr[n], acc[m][n], 0, 0, 0);
        if (more) write_stage(cur ^ 1);           // convert + ds_write late
        __syncthreads();
        cur ^= 1;
    }

    const int cr = (lane >> 4) * 4;
    const int cc = lane & 15;
    #pragma unroll
    for (int m = 0; m < MF; ++m)
        #pragma unroll
        for (int n = 0; n < 4; ++n)
            #pragma unroll
            for (int j = 0; j < 4; ++j) {
                size_t row = bm + wr * (BM / 2) + m * 16 + cr + j;
                size_t col = bn + wc * 64 + n * 16 + cc;
                float v = acc[m][n][j];
                if (OUT_BF16) ((unsigned short*)Cout)[row * N + col] = f2bf(v);
                else          ((float*)Cout)[row * N + col] = v;
            }
}

// Per-chunk ST[e][d] = sum_t v_ext[t][e]*phi(k)[t][d], e=0..32 (row 32 = ksum),
// PLUS fused exclusive chunk-prefix: the last-finishing block of each bh (8 blocks/bh,
// detected via device-scope atomic counter) scans that bh's 32 tiles -> bf16 cSt.
// No block ever waits (last-arriver pattern; no spin).
__global__ __launch_bounds__(256) void chunk_sum(const unsigned short* __restrict__ qkv,
                                                 float* __restrict__ cSf,
                                                 unsigned short* __restrict__ cSt,
                                                 unsigned int* __restrict__ cnt)
{
    __shared__ unsigned short Kt[4][DH][VTP];
    __shared__ unsigned short Vt[4][48][VTP];
    __shared__ unsigned int slast;
    const int tid = threadIdx.x;
    const int lane = tid & 63;
    const int wave = tid >> 6;
    const int chunk = blockIdx.x * 4 + wave;
    const int c = chunk & 31;
    const int h = (chunk >> 5) & 15;
    const int b = chunk >> 9;
    const int bh = blockIdx.x >> 3;            // 8 blocks per bh
    const size_t rowbase = ((size_t)(b * T_ + c * L_)) * (3 * D_) + h * DH;
    const int half = lane & 1;

    #pragma unroll
    for (int it = 0; it < 2; ++it) {
        int t = (lane >> 1) + it * 32;
        const unsigned short* kp = qkv + rowbase + (size_t)t * (3 * D_) + D_ + half * 16;
        const unsigned short* vp = qkv + rowbase + (size_t)t * (3 * D_) + 2 * D_ + half * 16;
        bf16x8 k0 = phi_frag(*(const bf16x8*)kp);
        bf16x8 k1 = phi_frag(*(const bf16x8*)(kp + 8));
        bf16x8 v0 = *(const bf16x8*)vp;
        bf16x8 v1 = *(const bf16x8*)(vp + 8);
        #pragma unroll
        for (int i = 0; i < 8; ++i) {
            Kt[wave][half * 16 + i][t]     = (unsigned short)k0[i];
            Kt[wave][half * 16 + 8 + i][t] = (unsigned short)k1[i];
            Vt[wave][half * 16 + i][t]     = (unsigned short)v0[i];
            Vt[wave][half * 16 + 8 + i][t] = (unsigned short)v1[i];
        }
    }
    Vt[wave][32][lane] = 0x3F80;   // ones row

    const int fr = lane & 15;
    const int fg = lane >> 4;
    f32x4 acc[3][2];
    #pragma unroll
    for (int m = 0; m < 3; ++m)
        #pragma unroll
        for (int n = 0; n < 2; ++n)
            acc[m][n] = (f32x4){0.f, 0.f, 0.f, 0.f};

    #pragma unroll
    for (int ks = 0; ks < 2; ++ks) {
        int toff = fg * 8 + ks * 32;
        bf16x8 av[3], bk[2];
        #pragma unroll
        for (int m = 0; m < 3; ++m) av[m] = *(const bf16x8*)&Vt[wave][m * 16 + fr][toff];
        #pragma unroll
        for (int n = 0; n < 2; ++n) bk[n] = *(const bf16x8*)&Kt[wave][n * 16 + fr][toff];
        #pragma unroll
        for (int m = 0; m < 3; ++m)
            #pragma unroll
            for (int n = 0; n < 2; ++n)
                acc[m][n] = __builtin_amdgcn_mfma_f32_16x16x32_bf16(av[m], bk[n], acc[m][n], 0, 0, 0);
    }

    float* outp = cSf + (size_t)chunk * CSZ;
    #pragma unroll
    for (int m = 0; m < 2; ++m)
        #pragma unroll
        for (int n = 0; n < 2; ++n)
            #pragma unroll
            for (int r = 0; r < 4; ++r)
                outp[(m * 16 + fg * 4 + r) * 32 + n * 16 + fr] = acc[m][n][r];
    if (fg == 0) {
        #pragma unroll
        for (int n = 0; n < 2; ++n)
            outp[32 * 32 + n * 16 + fr] = acc[2][n][0];
    }

    // ---- fused scan: last block of this bh does the exclusive prefix
    __threadfence();                 // release: our cSf stores device-visible
    __syncthreads();
    if (tid == 0)
        slast = (__hip_atomic_fetch_add(&cnt[bh], 1u, __ATOMIC_ACQ_REL,
                                        __HIP_MEMORY_SCOPE_AGENT) == 7u);
    __syncthreads();
    if (slast) {
        __threadfence();             // acquire: see other blocks' cSf stores
        const float* src = cSf + (size_t)bh * C_ * CSZ;
        unsigned short* dst = cSt + (size_t)bh * C_ * CSZ;
        #pragma unroll
        for (int u = 0; u < 5; ++u) {
            int e = tid + u * 256;
            if (e < CSZ) {
                float v[C_];
                #pragma unroll
                for (int cc = 0; cc < C_; ++cc) v[cc] = src[(size_t)cc * CSZ + e];
                float a = 0.f;
                #pragma unroll
                for (int cc = 0; cc < C_; ++cc) {
                    dst[(size_t)cc * CSZ + e] = f2bf(a);
                    a += v[cc];
                }
            }
        }
    }
}

// Per-chunk output via MFMA. 2 waves per chunk (row halves), 2 chunks per block.
__global__ __launch_bounds__(256) void chunk_out(const unsigned short* __restrict__ qkv,
                                                 const unsigned short* __restrict__ cSt,
                                                 unsigned short* __restrict__ attn)
{
    __shared__ unsigned short Vt[2][48][VTP];
    __shared__ unsigned short Am[4][32][VTP];
    const int tid = threadIdx.x;
    const int lane = tid & 63;
    const int wave = tid >> 6;
    const int ci = wave >> 1;
    const int wh = wave & 1;
    const int chunk = blockIdx.x * 2 + ci;
    const int c = chunk & 31;
    const int h = (chunk >> 5) & 15;
    const int b = chunk >> 9;
    const size_t rowbase = ((size_t)(b * T_ + c * L_)) * (3 * D_) + h * DH;
    const int fr = lane & 15;
    const int fg = lane >> 4;

    {
        int t = wh * 32 + (lane >> 1);
        int half = lane & 1;
        const unsigned short* vp = qkv + rowbase + (size_t)t * (3 * D_) + 2 * D_ + half * 16;
        bf16x8 v0 = *(const bf16x8*)vp;
        bf16x8 v1 = *(const bf16x8*)(vp + 8);
        #pragma unroll
        for (int i = 0; i < 8; ++i) {
            Vt[ci][half * 16 + i][t]     = (unsigned short)v0[i];
            Vt[ci][half * 16 + 8 + i][t] = (unsigned short)v1[i];
        }
        if (half == 0) Vt[ci][32][t] = 0x3F80;
    }

    bf16x8 aq[2];
    #pragma unroll
    for (int mm = 0; mm < 2; ++mm) {
        int m = wh * 2 + mm;
        const unsigned short* qp = qkv + rowbase + (size_t)(m * 16 + fr) * (3 * D_) + fg * 8;
        aq[mm] = phi_frag(*(const bf16x8*)qp);
    }
    bf16x8 bk[4];
    const int nmax = wh * 2 + 1;
    #pragma unroll
    for (int n = 0; n < 4; ++n) {
        if (n <= nmax) {
            const unsigned short* kp = qkv + rowbase + (size_t)(n * 16 + fr) * (3 * D_) + D_ + fg * 8;
            bk[n] = phi_frag(*(const bf16x8*)kp);
        }
    }
    bf16x8 bkv[3];
    #pragma unroll
    for (int n = 0; n < 3; ++n)
        bkv[n] = *(const bf16x8*)&cSt[(size_t)chunk * CSZ + (size_t)(n * 16 + fr) * 32 + fg * 8];

    f32x4 zero = (f32x4){0.f, 0.f, 0.f, 0.f};
    f32x4 acc[2][3];
    #pragma unroll
    for (int mm = 0; mm < 2; ++mm)
        #pragma unroll
        for (int n = 0; n < 3; ++n)
            acc[mm][n] = __builtin_amdgcn_mfma_f32_16x16x32_bf16(aq[mm], bkv[n], zero, 0, 0, 0);

    #pragma unroll
    for (int mm = 0; mm < 2; ++mm) {
        int m = wh * 2 + mm;
        #pragma unroll
        for (int n = 0; n < 4; ++n) {
            if (n <= m) {
                f32x4 s = __builtin_amdgcn_mfma_f32_16x16x32_bf16(aq[mm], bk[n], zero, 0, 0, 0);
                #pragma unroll
                for (int r = 0; r < 4; ++r) {
                    unsigned short v = f2bf(s[r]);
                    if (n == m && fr > fg * 4 + r) v = 0;
                    Am[wave][mm * 16 + fg * 4 + r][n * 16 + fr] = v;
                }
            }
        }
    }
    {
        int zc = wh ? 48 : 16;
        *(uint2*)&Am[wave][fr][zc + fg * 4] = (uint2){0u, 0u};
    }
    __syncthreads();

    #pragma unroll
    for (int ks = 0; ks < 2; ++ks) {
        if (ks <= wh) {
            bf16x8 bv[3];
            #pragma unroll
            for (int n = 0; n < 3; ++n)
                bv[n] = *(const bf16x8*)&Vt[ci][n * 16 + fr][fg * 8 + ks * 32];
            #pragma unroll
            for (int mm = 0; mm < 2; ++mm) {
                bf16x8 aa = *(const bf16x8*)&Am[wave][mm * 16 + fr][fg * 8 + ks * 32];
                #pragma unroll
                for (int n = 0; n < 3; ++n)
                    acc[mm][n] = __builtin_amdgcn_mfma_f32_16x16x32_bf16(aa, bv[n], acc[mm][n], 0, 0, 0);
            }
        }
    }

    #pragma unroll
    for (int mm = 0; mm < 2; ++mm) {
        float dn[4];
        #pragma unroll
        for (int r = 0; r < 4; ++r)
            dn[r] = __shfl(acc[mm][2][r], lane & 48);
        #pragma unroll
        for (int r = 0; r < 4; ++r) {
            float inv = 1.0f / fmaxf(dn[r], 1e-6f);
            #pragma unroll
            for (int n = 0; n < 2; ++n)
                Am[wave][mm * 16 + fg * 4 + r][n * 16 + fr] = f2bf(acc[mm][n][r] * inv);
        }
    }
    {
        int lrow = lane >> 1;
        int half = lane & 1;
        uint4 q0 = *(const uint4*)&Am[wave][lrow][half * 16];
        uint4 q1 = *(const uint4*)&Am[wave][lrow][half * 16 + 8];
        size_t grow = (size_t)(b * T_ + c * L_ + wh * 32 + lrow);
        unsigned short* dst = attn + grow * D_ + h * DH + half * 16;
        *(uint4*)dst = q0;
        *(uint4*)(dst + 8) = q1;
    }
}

extern "C" void kernel_launch(void* const* d_in, const int* in_sizes, int n_in,
                              void* d_out, int out_size, void* d_ws, size_t ws_size,
                              hipStream_t stream) {
    const float* x     = (const float*)d_in[0];
    const float* w_qkv = (const float*)d_in[1];
    const float* w_out = (const float*)d_in[2];
    float* out = (float*)d_out;

    char* ws = (char*)d_ws;
    unsigned short* qkvb  = (unsigned short*)ws;                 // 12,582,912 B
    unsigned short* attnb = (unsigned short*)(ws + 12582912);    //  4,194,304 B
    float* cSf            = (float*)(ws + 16777216);             //  4,325,376 B  [1024][1056] f32
    unsigned short* cSt   = (unsigned short*)(ws + 21102592);    //  2,162,688 B  [1024][1056] bf16
    unsigned int* cnt     = (unsigned int*)(ws + 23265280);      //        128 B  per-bh counters
    // total 23,265,408 B

    // per-bh last-arriver counters must be zero at every call (ws not re-poisoned)
    hipMemsetAsync(cnt, 0, 128, stream);

    // 1) QKV projection: fp32 x / fp32 w_qkv -> bf16 qkv (convert fused into staging)
    gemm_nt<64, true, true><<<dim3(4096 / 64, 1536 / 128), 256, 0, stream>>>(
        x, w_qkv, qkvb, 1536, 512);

    // 2) per-chunk local sums + fused last-block exclusive prefix scan
    chunk_sum<<<NC / 4, 256, 0, stream>>>(qkvb, cSf, cSt, cnt);

    // 3) per-chunk outputs -> bf16 attn
    chunk_out<<<NC / 2, 256, 0, stream>>>(qkvb, cSt, attnb);

    // 4) output projection: bf16 attn (gload_lds) / fp32 w_out -> fp32 out
    gemm_nt<64, false, false><<<dim3(4096 / 64, 512 / 128), 256, 0, stream>>>(
        attnb, w_out, out, 512, 512);
}

// Round 13
// 49.523 us; speedup vs baseline: 1.9347x; 1.9347x over previous
//
#include <hip/hip_runtime.h>
#include <hip/hip_bf16.h>
#include <math.h>

#define B_ 2
#define T_ 2048
#define D_ 512
#define H_ 16
#define DH 32
#define L_ 64
#define C_ 32
#define NC 1024    // total chunks
#define VTP 72     // LDS row stride (ushorts) for chunk kernels
#define CSZ 1056   // floats per chunk state tile (33 rows x 32)

typedef __attribute__((ext_vector_type(8))) short bf16x8;
typedef __attribute__((ext_vector_type(4))) float f32x4;
typedef __attribute__((ext_vector_type(4))) unsigned short u16x4;

#define AS1 __attribute__((address_space(1)))
#define AS3 __attribute__((address_space(3)))

__device__ __forceinline__ float bf2f(unsigned short u) {
    union { float f; unsigned int i; } v; v.i = ((unsigned int)u) << 16; return v.f;
}
__device__ __forceinline__ unsigned short f2bf(float f) {
    union { float f; unsigned int u; } v; v.f = f;
    unsigned int u = v.u;
    unsigned int r = u + 0x7FFFu + ((u >> 16) & 1u);
    return (unsigned short)(r >> 16);
}
__device__ __forceinline__ unsigned short f2bf_rne(float f) {
    __hip_bfloat16 h = __float2bfloat16(f);
    union { __hip_bfloat16 h; unsigned short u; } v; v.h = h; return v.u;
}
__device__ __forceinline__ bf16x8 phi_frag(bf16x8 in) {
    bf16x8 r;
    #pragma unroll
    for (int i = 0; i < 8; ++i) {
        float f = bf2f((unsigned short)in[i]);
        f = f > 0.f ? f + 1.f : __expf(f);
        r[i] = (short)f2bf(f);
    }
    return r;
}
__device__ __forceinline__ void gload_lds16(const unsigned short* g, unsigned short* l) {
    __builtin_amdgcn_global_load_lds((const AS1 unsigned int*)g, (AS3 unsigned int*)l, 16, 0, 0);
}

// ---- gemm1: qkv = x @ w_qkv^T. fp32 inputs, bf16 out. BM=64, BN=128, BK=64.
// Reg-staged fp32->bf16 (T14: load early, cvt+ds_write after MFMA). XOR-swizzled
// LDS (T2, byte ^= (row&7)<<4 on write AND read) -> 48KB LDS, 3 blocks/CU.
__global__ __launch_bounds__(256) void gemm_qkv(const float* __restrict__ A,
                                                const float* __restrict__ W,
                                                unsigned short* __restrict__ Cout)
{
    __shared__ unsigned short As[2][64][64];    // 16 KB
    __shared__ unsigned short Bs[2][128][64];   // 32 KB
    const int tid = threadIdx.x;
    const int lane = tid & 63;
    const int wave = tid >> 6;
    const int wr = wave >> 1, wc = wave & 1;
    const size_t bm = (size_t)blockIdx.x * 64;
    const size_t bn = (size_t)blockIdx.y * 128;

    const int srow = lane >> 4;            // 0..3
    const int scolf = (lane & 15) * 4;     // float col 0..60
    const float* ag = A + (bm + wave * 16 + srow) * (size_t)512 + scolf;
    const float* wg = W + (bn + wave * 32 + srow) * (size_t)512 + scolf;

    f32x4 aL[4];
    f32x4 wL[8];

    auto load_stage = [&](int k0) {
        #pragma unroll
        for (int i = 0; i < 4; ++i) aL[i] = *(const f32x4*)(ag + k0 + (size_t)(i * 4) * 512);
        #pragma unroll
        for (int i = 0; i < 8; ++i) wL[i] = *(const f32x4*)(wg + k0 + (size_t)(i * 4) * 512);
    };
    auto write_stage = [&](int buf) {
        #pragma unroll
        for (int i = 0; i < 4; ++i) {
            int row = wave * 16 + srow + i * 4;
            unsigned int cb = (unsigned int)((lane & 15) * 8) ^ (unsigned int)((row & 7) << 4);
            u16x4 o;
            o.x = f2bf_rne(aL[i][0]); o.y = f2bf_rne(aL[i][1]);
            o.z = f2bf_rne(aL[i][2]); o.w = f2bf_rne(aL[i][3]);
            *(u16x4*)((char*)&As[buf][row][0] + cb) = o;
        }
        #pragma unroll
        for (int i = 0; i < 8; ++i) {
            int row = wave * 32 + srow + i * 4;
            unsigned int cb = (unsigned int)((lane & 15) * 8) ^ (unsigned int)((row & 7) << 4);
            u16x4 o;
            o.x = f2bf_rne(wL[i][0]); o.y = f2bf_rne(wL[i][1]);
            o.z = f2bf_rne(wL[i][2]); o.w = f2bf_rne(wL[i][3]);
            *(u16x4*)((char*)&Bs[buf][row][0] + cb) = o;
        }
    };

    f32x4 acc[2][4];
    #pragma unroll
    for (int m = 0; m < 2; ++m)
        #pragma unroll
        for (int n = 0; n < 4; ++n)
            acc[m][n] = (f32x4){0.f, 0.f, 0.f, 0.f};

    const int rr = lane & 15;
    const int fgb = (lane >> 4) * 16;                  // byte offset of k-group
    const unsigned int akey = (unsigned int)((rr & 7) << 4);

    load_stage(0);
    write_stage(0);
    __syncthreads();
    int cur = 0;
    for (int k0 = 0; k0 < 512; k0 += 64) {
        const bool more = k0 + 64 < 512;
        if (more) load_stage(k0 + 64);     // issue next loads early; latency under MFMA
        #pragma unroll
        for (int kh = 0; kh < 2; ++kh) {
            const unsigned int cb = (unsigned int)(kh * 64 + fgb) ^ akey;
            bf16x8 af[2], bfr[4];
            #pragma unroll
            for (int m = 0; m < 2; ++m)
                af[m] = *(const bf16x8*)((const char*)&As[cur][wr * 32 + m * 16 + rr][0] + cb);
            #pragma unroll
            for (int n = 0; n < 4; ++n)
                bfr[n] = *(const bf16x8*)((const char*)&Bs[cur][wc * 64 + n * 16 + rr][0] + cb);
            #pragma unroll
            for (int m = 0; m < 2; ++m)
                #pragma unroll
                for (int n = 0; n < 4; ++n)
                    acc[m][n] = __builtin_amdgcn_mfma_f32_16x16x32_bf16(af[m], bfr[n], acc[m][n], 0, 0, 0);
        }
        if (more) write_stage(cur ^ 1);    // convert + ds_write late
        __syncthreads();
        cur ^= 1;
    }

    const int cr = (lane >> 4) * 4;
    const int cc = lane & 15;
    #pragma unroll
    for (int m = 0; m < 2; ++m)
        #pragma unroll
        for (int n = 0; n < 4; ++n)
            #pragma unroll
            for (int j = 0; j < 4; ++j) {
                size_t row = bm + wr * 32 + m * 16 + cr + j;
                size_t col = bn + wc * 64 + n * 16 + cc;
                Cout[row * 1536 + col] = f2bf(acc[m][n][j]);
            }
}

// ---- gemm2: out = attn @ w_out^T. A bf16 via global_load_lds; W fp32 reg-staged.
template<int BM, bool AF32, bool OUT_BF16>
__global__ __launch_bounds__(256) void gemm_nt(const void* __restrict__ Aptr,
                                               const float* __restrict__ Wf,
                                               void* __restrict__ Cout,
                                               int N, int K)
{
    constexpr int MF = BM / 32;
    constexpr int AF4 = BM / 32;
    __shared__ unsigned short As[2][BM][32];
    __shared__ unsigned short Bs[2][128][32];
    const int tid = threadIdx.x;
    const int lane = tid & 63;
    const int wave = tid >> 6;
    const int wr = wave >> 1;
    const int wc = wave & 1;
    const size_t bm = (size_t)blockIdx.x * BM;
    const size_t bn = (size_t)blockIdx.y * 128;

    const int r8 = lane >> 3;
    const int c4 = (lane & 7) * 4;
    const int lrow = lane >> 2;
    const int lcol = (lane & 3) * 8;

    const float* agf = nullptr;
    const unsigned short* agb = nullptr;
    if constexpr (AF32) agf = (const float*)Aptr + (bm + wave * (BM / 4) + r8) * (size_t)K + c4;
    else                agb = (const unsigned short*)Aptr + (bm + wave * (BM / 4) + lrow) * (size_t)K + lcol;
    const float* wgf = Wf + (bn + wave * 32 + r8) * (size_t)K + c4;

    f32x4 aL[AF4];
    f32x4 wL[4];

    auto load_stage = [&](int buf, int k0) {
        if constexpr (AF32) {
            #pragma unroll
            for (int i = 0; i < AF4; ++i)
                aL[i] = *(const f32x4*)(agf + k0 + (size_t)(i * 8) * K);
        } else {
            gload_lds16(agb + k0, &As[buf][wave * (BM / 4)][0]);
            if constexpr (BM / 4 == 32)
                gload_lds16(agb + (size_t)16 * K + k0, &As[buf][wave * (BM / 4) + 16][0]);
        }
        #pragma unroll
        for (int i = 0; i < 4; ++i)
            wL[i] = *(const f32x4*)(wgf + k0 + (size_t)(i * 8) * K);
    };
    auto write_stage = [&](int buf) {
        if constexpr (AF32) {
            #pragma unroll
            for (int i = 0; i < AF4; ++i) {
                u16x4 o;
                o.x = f2bf_rne(aL[i][0]); o.y = f2bf_rne(aL[i][1]);
                o.z = f2bf_rne(aL[i][2]); o.w = f2bf_rne(aL[i][3]);
                *(u16x4*)&As[buf][wave * (BM / 4) + r8 + i * 8][c4] = o;
            }
        }
        #pragma unroll
        for (int i = 0; i < 4; ++i) {
            u16x4 o;
            o.x = f2bf_rne(wL[i][0]); o.y = f2bf_rne(wL[i][1]);
            o.z = f2bf_rne(wL[i][2]); o.w = f2bf_rne(wL[i][3]);
            *(u16x4*)&Bs[buf][wave * 32 + r8 + i * 8][c4] = o;
        }
    };

    f32x4 acc[MF][4];
    #pragma unroll
    for (int m = 0; m < MF; ++m)
        #pragma unroll
        for (int n = 0; n < 4; ++n)
            acc[m][n] = (f32x4){0.f, 0.f, 0.f, 0.f};

    const int rr = lane & 15;
    const int kb = (lane >> 4) * 8;

    load_stage(0, 0);
    write_stage(0);
    __syncthreads();
    int cur = 0;
    for (int k0 = 0; k0 < K; k0 += 32) {
        const bool more = k0 + 32 < K;
        if (more) load_stage(cur ^ 1, k0 + 32);
        bf16x8 af[MF], bfr[4];
        #pragma unroll
        for (int m = 0; m < MF; ++m)
            af[m] = *(const bf16x8*)&As[cur][wr * (BM / 2) + m * 16 + rr][kb];
        #pragma unroll
        for (int n = 0; n < 4; ++n)
            bfr[n] = *(const bf16x8*)&Bs[cur][wc * 64 + n * 16 + rr][kb];
        #pragma unroll
        for (int m = 0; m < MF; ++m)
            #pragma unroll
            for (int n = 0; n < 4; ++n)
                acc[m][n] = __builtin_amdgcn_mfma_f32_16x16x32_bf16(af[m], bfr[n], acc[m][n], 0, 0, 0);
        if (more) write_stage(cur ^ 1);
        __syncthreads();
        cur ^= 1;
    }

    const int cr = (lane >> 4) * 4;
    const int cc = lane & 15;
    #pragma unroll
    for (int m = 0; m < MF; ++m)
        #pragma unroll
        for (int n = 0; n < 4; ++n)
            #pragma unroll
            for (int j = 0; j < 4; ++j) {
                size_t row = bm + wr * (BM / 2) + m * 16 + cr + j;
                size_t col = bn + wc * 64 + n * 16 + cc;
                float v = acc[m][n][j];
                if (OUT_BF16) ((unsigned short*)Cout)[row * N + col] = f2bf(v);
                else          ((float*)Cout)[row * N + col] = v;
            }
}

// Per-chunk ST[e][d] = sum_t v_ext[t][e]*phi(k)[t][d], e=0..32 (row 32 = ksum).
__global__ __launch_bounds__(256) void chunk_sum(const unsigned short* __restrict__ qkv,
                                                 float* __restrict__ cSf)
{
    __shared__ unsigned short Kt[4][DH][VTP];
    __shared__ unsigned short Vt[4][48][VTP];
    const int tid = threadIdx.x;
    const int lane = tid & 63;
    const int wave = tid >> 6;
    const int chunk = blockIdx.x * 4 + wave;
    const int c = chunk & 31;
    const int h = (chunk >> 5) & 15;
    const int b = chunk >> 9;
    const size_t rowbase = ((size_t)(b * T_ + c * L_)) * (3 * D_) + h * DH;
    const int half = lane & 1;

    #pragma unroll
    for (int it = 0; it < 2; ++it) {
        int t = (lane >> 1) + it * 32;
        const unsigned short* kp = qkv + rowbase + (size_t)t * (3 * D_) + D_ + half * 16;
        const unsigned short* vp = qkv + rowbase + (size_t)t * (3 * D_) + 2 * D_ + half * 16;
        bf16x8 k0 = phi_frag(*(const bf16x8*)kp);
        bf16x8 k1 = phi_frag(*(const bf16x8*)(kp + 8));
        bf16x8 v0 = *(const bf16x8*)vp;
        bf16x8 v1 = *(const bf16x8*)(vp + 8);
        #pragma unroll
        for (int i = 0; i < 8; ++i) {
            Kt[wave][half * 16 + i][t]     = (unsigned short)k0[i];
            Kt[wave][half * 16 + 8 + i][t] = (unsigned short)k1[i];
            Vt[wave][half * 16 + i][t]     = (unsigned short)v0[i];
            Vt[wave][half * 16 + 8 + i][t] = (unsigned short)v1[i];
        }
    }
    Vt[wave][32][lane] = 0x3F80;   // ones row

    const int fr = lane & 15;
    const int fg = lane >> 4;
    f32x4 acc[3][2];
    #pragma unroll
    for (int m = 0; m < 3; ++m)
        #pragma unroll
        for (int n = 0; n < 2; ++n)
            acc[m][n] = (f32x4){0.f, 0.f, 0.f, 0.f};

    #pragma unroll
    for (int ks = 0; ks < 2; ++ks) {
        int toff = fg * 8 + ks * 32;
        bf16x8 av[3], bk[2];
        #pragma unroll
        for (int m = 0; m < 3; ++m) av[m] = *(const bf16x8*)&Vt[wave][m * 16 + fr][toff];
        #pragma unroll
        for (int n = 0; n < 2; ++n) bk[n] = *(const bf16x8*)&Kt[wave][n * 16 + fr][toff];
        #pragma unroll
        for (int m = 0; m < 3; ++m)
            #pragma unroll
            for (int n = 0; n < 2; ++n)
                acc[m][n] = __builtin_amdgcn_mfma_f32_16x16x32_bf16(av[m], bk[n], acc[m][n], 0, 0, 0);
    }

    float* outp = cSf + (size_t)chunk * CSZ;
    #pragma unroll
    for (int m = 0; m < 2; ++m)
        #pragma unroll
        for (int n = 0; n < 2; ++n)
            #pragma unroll
            for (int r = 0; r < 4; ++r)
                outp[(m * 16 + fg * 4 + r) * 32 + n * 16 + fr] = acc[m][n][r];
    if (fg == 0) {
        #pragma unroll
        for (int n = 0; n < 2; ++n)
            outp[32 * 32 + n * 16 + fr] = acc[2][n][0];
    }
}

// Exclusive prefix over chunks; emit bf16 state cSt[chunk][e*32+d].
__global__ __launch_bounds__(256) void chunk_scan(const float* __restrict__ cSf,
                                                  unsigned short* __restrict__ cSt)
{
    int idx = blockIdx.x * 256 + threadIdx.x;     // 32*1056 = 33792 exactly
    int bh = idx / CSZ;
    int r  = idx % CSZ;
    const float* src = cSf + (size_t)bh * C_ * CSZ + r;
    unsigned short* dst = cSt + (size_t)bh * C_ * CSZ + r;
    float v[C_];
    #pragma unroll
    for (int c = 0; c < C_; ++c) v[c] = src[(size_t)c * CSZ];
    float acc = 0.f;
    #pragma unroll
    for (int c = 0; c < C_; ++c) {
        dst[(size_t)c * CSZ] = f2bf(acc);
        acc += v[c];
    }
}

// Per-chunk output via MFMA. 2 waves per chunk (row halves), 2 chunks per block.
__global__ __launch_bounds__(256) void chunk_out(const unsigned short* __restrict__ qkv,
                                                 const unsigned short* __restrict__ cSt,
                                                 unsigned short* __restrict__ attn)
{
    __shared__ unsigned short Vt[2][48][VTP];
    __shared__ unsigned short Am[4][32][VTP];
    const int tid = threadIdx.x;
    const int lane = tid & 63;
    const int wave = tid >> 6;
    const int ci = wave >> 1;
    const int wh = wave & 1;
    const int chunk = blockIdx.x * 2 + ci;
    const int c = chunk & 31;
    const int h = (chunk >> 5) & 15;
    const int b = chunk >> 9;
    const size_t rowbase = ((size_t)(b * T_ + c * L_)) * (3 * D_) + h * DH;
    const int fr = lane & 15;
    const int fg = lane >> 4;

    {
        int t = wh * 32 + (lane >> 1);
        int half = lane & 1;
        const unsigned short* vp = qkv + rowbase + (size_t)t * (3 * D_) + 2 * D_ + half * 16;
        bf16x8 v0 = *(const bf16x8*)vp;
        bf16x8 v1 = *(const bf16x8*)(vp + 8);
        #pragma unroll
        for (int i = 0; i < 8; ++i) {
            Vt[ci][half * 16 + i][t]     = (unsigned short)v0[i];
            Vt[ci][half * 16 + 8 + i][t] = (unsigned short)v1[i];
        }
        if (half == 0) Vt[ci][32][t] = 0x3F80;
    }

    bf16x8 aq[2];
    #pragma unroll
    for (int mm = 0; mm < 2; ++mm) {
        int m = wh * 2 + mm;
        const unsigned short* qp = qkv + rowbase + (size_t)(m * 16 + fr) * (3 * D_) + fg * 8;
        aq[mm] = phi_frag(*(const bf16x8*)qp);
    }
    bf16x8 bk[4];
    const int nmax = wh * 2 + 1;
    #pragma unroll
    for (int n = 0; n < 4; ++n) {
        if (n <= nmax) {
            const unsigned short* kp = qkv + rowbase + (size_t)(n * 16 + fr) * (3 * D_) + D_ + fg * 8;
            bk[n] = phi_frag(*(const bf16x8*)kp);
        }
    }
    bf16x8 bkv[3];
    #pragma unroll
    for (int n = 0; n < 3; ++n)
        bkv[n] = *(const bf16x8*)&cSt[(size_t)chunk * CSZ + (size_t)(n * 16 + fr) * 32 + fg * 8];

    f32x4 zero = (f32x4){0.f, 0.f, 0.f, 0.f};
    f32x4 acc[2][3];
    #pragma unroll
    for (int mm = 0; mm < 2; ++mm)
        #pragma unroll
        for (int n = 0; n < 3; ++n)
            acc[mm][n] = __builtin_amdgcn_mfma_f32_16x16x32_bf16(aq[mm], bkv[n], zero, 0, 0, 0);

    #pragma unroll
    for (int mm = 0; mm < 2; ++mm) {
        int m = wh * 2 + mm;
        #pragma unroll
        for (int n = 0; n < 4; ++n) {
            if (n <= m) {
                f32x4 s = __builtin_amdgcn_mfma_f32_16x16x32_bf16(aq[mm], bk[n], zero, 0, 0, 0);
                #pragma unroll
                for (int r = 0; r < 4; ++r) {
                    unsigned short v = f2bf(s[r]);
                    if (n == m && fr > fg * 4 + r) v = 0;
                    Am[wave][mm * 16 + fg * 4 + r][n * 16 + fr] = v;
                }
            }
        }
    }
    {
        int zc = wh ? 48 : 16;
        *(uint2*)&Am[wave][fr][zc + fg * 4] = (uint2){0u, 0u};
    }
    __syncthreads();

    #pragma unroll
    for (int ks = 0; ks < 2; ++ks) {
        if (ks <= wh) {
            bf16x8 bv[3];
            #pragma unroll
            for (int n = 0; n < 3; ++n)
                bv[n] = *(const bf16x8*)&Vt[ci][n * 16 + fr][fg * 8 + ks * 32];
            #pragma unroll
            for (int mm = 0; mm < 2; ++mm) {
                bf16x8 aa = *(const bf16x8*)&Am[wave][mm * 16 + fr][fg * 8 + ks * 32];
                #pragma unroll
                for (int n = 0; n < 3; ++n)
                    acc[mm][n] = __builtin_amdgcn_mfma_f32_16x16x32_bf16(aa, bv[n], acc[mm][n], 0, 0, 0);
            }
        }
    }

    #pragma unroll
    for (int mm = 0; mm < 2; ++mm) {
        float dn[4];
        #pragma unroll
        for (int r = 0; r < 4; ++r)
            dn[r] = __shfl(acc[mm][2][r], lane & 48);
        #pragma unroll
        for (int r = 0; r < 4; ++r) {
            float inv = 1.0f / fmaxf(dn[r], 1e-6f);
            #pragma unroll
            for (int n = 0; n < 2; ++n)
                Am[wave][mm * 16 + fg * 4 + r][n * 16 + fr] = f2bf(acc[mm][n][r] * inv);
        }
    }
    {
        int lrow = lane >> 1;
        int half = lane & 1;
        uint4 q0 = *(const uint4*)&Am[wave][lrow][half * 16];
        uint4 q1 = *(const uint4*)&Am[wave][lrow][half * 16 + 8];
        size_t grow = (size_t)(b * T_ + c * L_ + wh * 32 + lrow);
        unsigned short* dst = attn + grow * D_ + h * DH + half * 16;
        *(uint4*)dst = q0;
        *(uint4*)(dst + 8) = q1;
    }
}

extern "C" void kernel_launch(void* const* d_in, const int* in_sizes, int n_in,
                              void* d_out, int out_size, void* d_ws, size_t ws_size,
                              hipStream_t stream) {
    const float* x     = (const float*)d_in[0];
    const float* w_qkv = (const float*)d_in[1];
    const float* w_out = (const float*)d_in[2];
    float* out = (float*)d_out;

    char* ws = (char*)d_ws;
    unsigned short* qkvb  = (unsigned short*)ws;                 // 12,582,912 B
    unsigned short* attnb = (unsigned short*)(ws + 12582912);    //  4,194,304 B
    float* cSf            = (float*)(ws + 16777216);             //  4,325,376 B  [1024][1056] f32
    unsigned short* cSt   = (unsigned short*)(ws + 21102592);    //  2,162,688 B  [1024][1056] bf16
    // total 23,265,280 B

    // 1) QKV projection: fp32 x / fp32 w_qkv -> bf16 qkv (BK=64, XOR-swizzled LDS)
    gemm_qkv<<<dim3(4096 / 64, 1536 / 128), 256, 0, stream>>>(x, w_qkv, qkvb);

    // 2) per-chunk local sums
    chunk_sum<<<NC / 4, 256, 0, stream>>>(qkvb, cSf);

    // 3) exclusive prefix over chunks (dedicated kernel)
    chunk_scan<<<132, 256, 0, stream>>>(cSf, cSt);

    // 4) per-chunk outputs -> bf16 attn
    chunk_out<<<NC / 2, 256, 0, stream>>>(qkvb, cSt, attnb);

    // 5) output projection: bf16 attn (gload_lds) / fp32 w_out -> fp32 out
    gemm_nt<64, false, false><<<dim3(4096 / 64, 512 / 128), 256, 0, stream>>>(
        attnb, w_out, out, 512, 512);
}

// Round 14
// 49.031 us; speedup vs baseline: 1.9541x; 1.0100x over previous
//
#include <hip/hip_runtime.h>
#include <hip/hip_bf16.h>
#include <math.h>

#define B_ 2
#define T_ 2048
#define D_ 512
#define H_ 16
#define DH 32
#define L_ 64
#define C_ 32
#define NC 1024    // total chunks
#define VTP 72     // LDS row stride (ushorts) for chunk kernels
#define CSZ 1056   // floats per chunk state tile (33 rows x 32)

typedef __attribute__((ext_vector_type(8))) short bf16x8;
typedef __attribute__((ext_vector_type(4))) float f32x4;
typedef __attribute__((ext_vector_type(4))) unsigned short u16x4;

#define AS1 __attribute__((address_space(1)))
#define AS3 __attribute__((address_space(3)))

__device__ __forceinline__ float bf2f(unsigned short u) {
    union { float f; unsigned int i; } v; v.i = ((unsigned int)u) << 16; return v.f;
}
__device__ __forceinline__ unsigned short f2bf(float f) {
    union { float f; unsigned int u; } v; v.f = f;
    unsigned int u = v.u;
    unsigned int r = u + 0x7FFFu + ((u >> 16) & 1u);
    return (unsigned short)(r >> 16);
}
__device__ __forceinline__ unsigned short f2bf_rne(float f) {
    __hip_bfloat16 h = __float2bfloat16(f);
    union { __hip_bfloat16 h; unsigned short u; } v; v.h = h; return v.u;
}
__device__ __forceinline__ bf16x8 phi_frag(bf16x8 in) {
    bf16x8 r;
    #pragma unroll
    for (int i = 0; i < 8; ++i) {
        float f = bf2f((unsigned short)in[i]);
        f = f > 0.f ? f + 1.f : __expf(f);
        r[i] = (short)f2bf(f);
    }
    return r;
}
__device__ __forceinline__ void gload_lds16(const unsigned short* g, unsigned short* l) {
    __builtin_amdgcn_global_load_lds((const AS1 unsigned int*)g, (AS3 unsigned int*)l, 16, 0, 0);
}

// C[m][n] = sum_k A[m][k]*W[n][k]; BMx128 tile, 4 waves (2x2), 16x16x32 bf16 MFMA.
// W is always fp32, converted during reg-staging (T14: load early, cvt+ds_write late).
// A is fp32 (reg-staged convert) when AF32, else bf16 via async global_load_lds.
template<int BM, bool AF32, bool OUT_BF16>
__global__ __launch_bounds__(256) void gemm_nt(const void* __restrict__ Aptr,
                                               const float* __restrict__ Wf,
                                               void* __restrict__ Cout,
                                               int N, int K)
{
    constexpr int MF = BM / 32;        // m-fragments per wave
    constexpr int AF4 = BM / 32;       // float4 loads per lane for fp32 A staging
    __shared__ unsigned short As[2][BM][32];
    __shared__ unsigned short Bs[2][128][32];
    const int tid = threadIdx.x;
    const int lane = tid & 63;
    const int wave = tid >> 6;
    const int wr = wave >> 1;
    const int wc = wave & 1;
    const size_t bm = (size_t)blockIdx.x * BM;
    const size_t bn = (size_t)blockIdx.y * 128;

    const int r8 = lane >> 3;          // 0..7 (f32 staging row-in-group)
    const int c4 = (lane & 7) * 4;     // f32 staging col (floats)
    const int lrow = lane >> 2;        // bf16 gload row
    const int lcol = (lane & 3) * 8;   // bf16 gload col

    const float* agf = nullptr;
    const unsigned short* agb = nullptr;
    if constexpr (AF32) agf = (const float*)Aptr + (bm + wave * (BM / 4) + r8) * (size_t)K + c4;
    else                agb = (const unsigned short*)Aptr + (bm + wave * (BM / 4) + lrow) * (size_t)K + lcol;
    const float* wgf = Wf + (bn + wave * 32 + r8) * (size_t)K + c4;

    f32x4 aL[AF4];
    f32x4 wL[4];

    auto load_stage = [&](int buf, int k0) {
        if constexpr (AF32) {
            #pragma unroll
            for (int i = 0; i < AF4; ++i)
                aL[i] = *(const f32x4*)(agf + k0 + (size_t)(i * 8) * K);
        } else {
            gload_lds16(agb + k0, &As[buf][wave * (BM / 4)][0]);
            if constexpr (BM / 4 == 32)
                gload_lds16(agb + (size_t)16 * K + k0, &As[buf][wave * (BM / 4) + 16][0]);
        }
        #pragma unroll
        for (int i = 0; i < 4; ++i)
            wL[i] = *(const f32x4*)(wgf + k0 + (size_t)(i * 8) * K);
    };
    auto write_stage = [&](int buf) {
        if constexpr (AF32) {
            #pragma unroll
            for (int i = 0; i < AF4; ++i) {
                u16x4 o;
                o.x = f2bf_rne(aL[i][0]); o.y = f2bf_rne(aL[i][1]);
                o.z = f2bf_rne(aL[i][2]); o.w = f2bf_rne(aL[i][3]);
                *(u16x4*)&As[buf][wave * (BM / 4) + r8 + i * 8][c4] = o;
            }
        }
        #pragma unroll
        for (int i = 0; i < 4; ++i) {
            u16x4 o;
            o.x = f2bf_rne(wL[i][0]); o.y = f2bf_rne(wL[i][1]);
            o.z = f2bf_rne(wL[i][2]); o.w = f2bf_rne(wL[i][3]);
            *(u16x4*)&Bs[buf][wave * 32 + r8 + i * 8][c4] = o;
        }
    };

    f32x4 acc[MF][4];
    #pragma unroll
    for (int m = 0; m < MF; ++m)
        #pragma unroll
        for (int n = 0; n < 4; ++n)
            acc[m][n] = (f32x4){0.f, 0.f, 0.f, 0.f};

    const int rr = lane & 15;
    const int kb = (lane >> 4) * 8;

    load_stage(0, 0);
    write_stage(0);
    __syncthreads();
    int cur = 0;
    for (int k0 = 0; k0 < K; k0 += 32) {
        const bool more = k0 + 32 < K;
        if (more) load_stage(cur ^ 1, k0 + 32);   // issue loads early (latency under MFMA)
        bf16x8 af[MF], bfr[4];
        #pragma unroll
        for (int m = 0; m < MF; ++m)
            af[m] = *(const bf16x8*)&As[cur][wr * (BM / 2) + m * 16 + rr][kb];
        #pragma unroll
        for (int n = 0; n < 4; ++n)
            bfr[n] = *(const bf16x8*)&Bs[cur][wc * 64 + n * 16 + rr][kb];
        #pragma unroll
        for (int m = 0; m < MF; ++m)
            #pragma unroll
            for (int n = 0; n < 4; ++n)
                acc[m][n] = __builtin_amdgcn_mfma_f32_16x16x32_bf16(af[m], bfr[n], acc[m][n], 0, 0, 0);
        if (more) write_stage(cur ^ 1);           // convert + ds_write late
        __syncthreads();
        cur ^= 1;
    }

    const int cr = (lane >> 4) * 4;
    const int cc = lane & 15;
    #pragma unroll
    for (int m = 0; m < MF; ++m)
        #pragma unroll
        for (int n = 0; n < 4; ++n)
            #pragma unroll
            for (int j = 0; j < 4; ++j) {
                size_t row = bm + wr * (BM / 2) + m * 16 + cr + j;
                size_t col = bn + wc * 64 + n * 16 + cc;
                float v = acc[m][n][j];
                if (OUT_BF16) ((unsigned short*)Cout)[row * N + col] = f2bf(v);
                else          ((float*)Cout)[row * N + col] = v;
            }
}

// Per-chunk ST[e][d] = sum_t v_ext[t][e]*phi(k)[t][d], e=0..32 (row 32 = ksum).
__global__ __launch_bounds__(256) void chunk_sum(const unsigned short* __restrict__ qkv,
                                                 float* __restrict__ cSf)
{
    __shared__ unsigned short Kt[4][DH][VTP];
    __shared__ unsigned short Vt[4][48][VTP];
    const int tid = threadIdx.x;
    const int lane = tid & 63;
    const int wave = tid >> 6;
    const int chunk = blockIdx.x * 4 + wave;
    const int c = chunk & 31;
    const int h = (chunk >> 5) & 15;
    const int b = chunk >> 9;
    const size_t rowbase = ((size_t)(b * T_ + c * L_)) * (3 * D_) + h * DH;
    const int half = lane & 1;

    #pragma unroll
    for (int it = 0; it < 2; ++it) {
        int t = (lane >> 1) + it * 32;
        const unsigned short* kp = qkv + rowbase + (size_t)t * (3 * D_) + D_ + half * 16;
        const unsigned short* vp = qkv + rowbase + (size_t)t * (3 * D_) + 2 * D_ + half * 16;
        bf16x8 k0 = phi_frag(*(const bf16x8*)kp);
        bf16x8 k1 = phi_frag(*(const bf16x8*)(kp + 8));
        bf16x8 v0 = *(const bf16x8*)vp;
        bf16x8 v1 = *(const bf16x8*)(vp + 8);
        #pragma unroll
        for (int i = 0; i < 8; ++i) {
            Kt[wave][half * 16 + i][t]     = (unsigned short)k0[i];
            Kt[wave][half * 16 + 8 + i][t] = (unsigned short)k1[i];
            Vt[wave][half * 16 + i][t]     = (unsigned short)v0[i];
            Vt[wave][half * 16 + 8 + i][t] = (unsigned short)v1[i];
        }
    }
    Vt[wave][32][lane] = 0x3F80;   // ones row

    const int fr = lane & 15;
    const int fg = lane >> 4;
    f32x4 acc[3][2];
    #pragma unroll
    for (int m = 0; m < 3; ++m)
        #pragma unroll
        for (int n = 0; n < 2; ++n)
            acc[m][n] = (f32x4){0.f, 0.f, 0.f, 0.f};

    #pragma unroll
    for (int ks = 0; ks < 2; ++ks) {
        int toff = fg * 8 + ks * 32;
        bf16x8 av[3], bk[2];
        #pragma unroll
        for (int m = 0; m < 3; ++m) av[m] = *(const bf16x8*)&Vt[wave][m * 16 + fr][toff];
        #pragma unroll
        for (int n = 0; n < 2; ++n) bk[n] = *(const bf16x8*)&Kt[wave][n * 16 + fr][toff];
        #pragma unroll
        for (int m = 0; m < 3; ++m)
            #pragma unroll
            for (int n = 0; n < 2; ++n)
                acc[m][n] = __builtin_amdgcn_mfma_f32_16x16x32_bf16(av[m], bk[n], acc[m][n], 0, 0, 0);
    }

    float* outp = cSf + (size_t)chunk * CSZ;
    #pragma unroll
    for (int m = 0; m < 2; ++m)
        #pragma unroll
        for (int n = 0; n < 2; ++n)
            #pragma unroll
            for (int r = 0; r < 4; ++r)
                outp[(m * 16 + fg * 4 + r) * 32 + n * 16 + fr] = acc[m][n][r];
    if (fg == 0) {
        #pragma unroll
        for (int n = 0; n < 2; ++n)
            outp[32 * 32 + n * 16 + fr] = acc[2][n][0];
    }
}

// Exclusive prefix over chunks; emit bf16 state cSt[chunk][e*32+d].
__global__ __launch_bounds__(256) void chunk_scan(const float* __restrict__ cSf,
                                                  unsigned short* __restrict__ cSt)
{
    int idx = blockIdx.x * 256 + threadIdx.x;     // 32*1056 = 33792 exactly
    int bh = idx / CSZ;
    int r  = idx % CSZ;
    const float* src = cSf + (size_t)bh * C_ * CSZ + r;
    unsigned short* dst = cSt + (size_t)bh * C_ * CSZ + r;
    float v[C_];
    #pragma unroll
    for (int c = 0; c < C_; ++c) v[c] = src[(size_t)c * CSZ];
    float acc = 0.f;
    #pragma unroll
    for (int c = 0; c < C_; ++c) {
        dst[(size_t)c * CSZ] = f2bf(acc);
        acc += v[c];
    }
}

// Per-chunk output via MFMA. ONE chunk per block; 4 waves, wave w owns m-tile w
// (rows w*16..w*16+15). Same 40 MFMAs/chunk as before, but 1024 blocks = 4/CU.
__global__ __launch_bounds__(256) void chunk_out(const unsigned short* __restrict__ qkv,
                                                 const unsigned short* __restrict__ cSt,
                                                 unsigned short* __restrict__ attn)
{
    __shared__ unsigned short Vt[48][VTP];
    __shared__ unsigned short Am[4][16][VTP];
    const int tid = threadIdx.x;
    const int lane = tid & 63;
    const int w = tid >> 6;            // wave = m-tile index
    const int chunk = blockIdx.x;
    const int c = chunk & 31;
    const int h = (chunk >> 5) & 15;
    const int b = chunk >> 9;
    const size_t rowbase = ((size_t)(b * T_ + c * L_)) * (3 * D_) + h * DH;
    const int fr = lane & 15;
    const int fg = lane >> 4;

    // Vt build: wave w covers t = w*16..w*16+15; quarter q covers V cols q*8..q*8+7
    {
        int t = w * 16 + (lane >> 2);
        int q = lane & 3;
        const unsigned short* vp = qkv + rowbase + (size_t)t * (3 * D_) + 2 * D_ + q * 8;
        bf16x8 v0 = *(const bf16x8*)vp;
        #pragma unroll
        for (int i = 0; i < 8; ++i)
            Vt[q * 8 + i][t] = (unsigned short)v0[i];
        if (q == 0) Vt[32][t] = 0x3F80;   // ones row
    }

    // Q fragment (m-tile w), phi applied in-register
    bf16x8 aq;
    {
        const unsigned short* qp = qkv + rowbase + (size_t)(w * 16 + fr) * (3 * D_) + fg * 8;
        aq = phi_frag(*(const bf16x8*)qp);
    }
    // K fragments for col tiles n <= w
    bf16x8 bk[4];
    #pragma unroll
    for (int n = 0; n < 4; ++n) {
        if (n <= w) {
            const unsigned short* kp = qkv + rowbase + (size_t)(n * 16 + fr) * (3 * D_) + D_ + fg * 8;
            bk[n] = phi_frag(*(const bf16x8*)kp);
        }
    }
    // prefix state fragments direct from global cSt (rows e, incl. ks0 at e=32)
    bf16x8 bkv[3];
    #pragma unroll
    for (int n = 0; n < 3; ++n)
        bkv[n] = *(const bf16x8*)&cSt[(size_t)chunk * CSZ + (size_t)(n * 16 + fr) * 32 + fg * 8];

    // acc = Q @ KV0_ext  (output col 32 = den contribution q.ks0)
    f32x4 zero = (f32x4){0.f, 0.f, 0.f, 0.f};
    f32x4 acc[3];
    #pragma unroll
    for (int n = 0; n < 3; ++n)
        acc[n] = __builtin_amdgcn_mfma_f32_16x16x32_bf16(aq, bkv[n], zero, 0, 0, 0);

    // S tiles (lower triangle), masked, to LDS as bf16
    #pragma unroll
    for (int n = 0; n < 4; ++n) {
        if (n <= w) {
            f32x4 s = __builtin_amdgcn_mfma_f32_16x16x32_bf16(aq, bk[n], zero, 0, 0, 0);
            #pragma unroll
            for (int r = 0; r < 4; ++r) {
                unsigned short v = f2bf(s[r]);
                if (n == w && fr > fg * 4 + r) v = 0;
                Am[w][fg * 4 + r][n * 16 + fr] = v;
            }
        }
    }
    // even waves: zero the tile just above the diagonal that the K=32 A@V step reads
    if ((w & 1) == 0) {
        int zc = (w + 1) * 16;
        *(uint2*)&Am[w][lane >> 2][zc + (lane & 3) * 4] = (uint2){0u, 0u};
    }
    __syncthreads();   // Vt is cross-wave; Am is per-wave

    // acc += A_masked @ V_ext  (ks <= w>>1: rows 0-1 need k 0..31 only)
    #pragma unroll
    for (int ks = 0; ks < 2; ++ks) {
        if (ks <= (w >> 1)) {
            bf16x8 bv[3];
            #pragma unroll
            for (int n = 0; n < 3; ++n)
                bv[n] = *(const bf16x8*)&Vt[n * 16 + fr][fg * 8 + ks * 32];
            bf16x8 aa = *(const bf16x8*)&Am[w][fr][fg * 8 + ks * 32];
            #pragma unroll
            for (int n = 0; n < 3; ++n)
                acc[n] = __builtin_amdgcn_mfma_f32_16x16x32_bf16(aa, bv[n], acc[n], 0, 0, 0);
        }
    }

    // den broadcast (col 32 lives in lanes fr==0), divide, stage out via LDS
    float dn[4];
    #pragma unroll
    for (int r = 0; r < 4; ++r)
        dn[r] = __shfl(acc[2][r], lane & 48);
    #pragma unroll
    for (int r = 0; r < 4; ++r) {
        float inv = 1.0f / fmaxf(dn[r], 1e-6f);
        #pragma unroll
        for (int n = 0; n < 2; ++n)
            Am[w][fg * 4 + r][n * 16 + fr] = f2bf(acc[n][r] * inv);
    }
    // coalesced store: lane writes 16B (8 cols) of one row
    {
        int lrow = lane >> 2;
        int q = lane & 3;
        uint4 o = *(const uint4*)&Am[w][lrow][q * 8];
        size_t grow = (size_t)(b * T_ + c * L_ + w * 16 + lrow);
        *(uint4*)(attn + grow * D_ + h * DH + q * 8) = o;
    }
}

extern "C" void kernel_launch(void* const* d_in, const int* in_sizes, int n_in,
                              void* d_out, int out_size, void* d_ws, size_t ws_size,
                              hipStream_t stream) {
    const float* x     = (const float*)d_in[0];
    const float* w_qkv = (const float*)d_in[1];
    const float* w_out = (const float*)d_in[2];
    float* out = (float*)d_out;

    char* ws = (char*)d_ws;
    unsigned short* qkvb  = (unsigned short*)ws;                 // 12,582,912 B
    unsigned short* attnb = (unsigned short*)(ws + 12582912);    //  4,194,304 B
    float* cSf            = (float*)(ws + 16777216);             //  4,325,376 B  [1024][1056] f32
    unsigned short* cSt   = (unsigned short*)(ws + 21102592);    //  2,162,688 B  [1024][1056] bf16
    // total 23,265,280 B

    // 1) QKV projection: fp32 x / fp32 w_qkv -> bf16 qkv (convert fused into staging)
    gemm_nt<64, true, true><<<dim3(4096 / 64, 1536 / 128), 256, 0, stream>>>(
        x, w_qkv, qkvb, 1536, 512);

    // 2) per-chunk local sums
    chunk_sum<<<NC / 4, 256, 0, stream>>>(qkvb, cSf);

    // 3) exclusive prefix over chunks (dedicated kernel)
    chunk_scan<<<132, 256, 0, stream>>>(cSf, cSt);

    // 4) per-chunk outputs -> bf16 attn (1 chunk/block, 4 blocks/CU)
    chunk_out<<<NC, 256, 0, stream>>>(qkvb, cSt, attnb);

    // 5) output projection: bf16 attn (gload_lds) / fp32 w_out -> fp32 out
    gemm_nt<64, false, false><<<dim3(4096 / 64, 512 / 128), 256, 0, stream>>>(
        attnb, w_out, out, 512, 512);
}

// Round 15
// 47.574 us; speedup vs baseline: 2.0139x; 1.0306x over previous
//
#include <hip/hip_runtime.h>
#include <hip/hip_bf16.h>
#include <math.h>

#define B_ 2
#define T_ 2048
#define D_ 512
#define H_ 16
#define DH 32
#define L_ 64
#define C_ 32
#define NC 1024    // total chunks
#define VTP 72     // LDS row stride (ushorts) for chunk kernels
#define CSZ 1056   // floats per chunk state tile (33 rows x 32)

typedef __attribute__((ext_vector_type(8))) short bf16x8;
typedef __attribute__((ext_vector_type(4))) float f32x4;
typedef __attribute__((ext_vector_type(4))) unsigned short u16x4;

#define AS1 __attribute__((address_space(1)))
#define AS3 __attribute__((address_space(3)))

__device__ __forceinline__ float bf2f(unsigned short u) {
    union { float f; unsigned int i; } v; v.i = ((unsigned int)u) << 16; return v.f;
}
__device__ __forceinline__ unsigned short f2bf(float f) {
    union { float f; unsigned int u; } v; v.f = f;
    unsigned int u = v.u;
    unsigned int r = u + 0x7FFFu + ((u >> 16) & 1u);
    return (unsigned short)(r >> 16);
}
__device__ __forceinline__ unsigned short f2bf_rne(float f) {
    __hip_bfloat16 h = __float2bfloat16(f);
    union { __hip_bfloat16 h; unsigned short u; } v; v.h = h; return v.u;
}
__device__ __forceinline__ float phi_s(float f) {
    return f > 0.f ? f + 1.f : __expf(f);
}
__device__ __forceinline__ bf16x8 phi_frag(bf16x8 in) {
    bf16x8 r;
    #pragma unroll
    for (int i = 0; i < 8; ++i) {
        float f = bf2f((unsigned short)in[i]);
        r[i] = (short)f2bf(phi_s(f));
    }
    return r;
}
__device__ __forceinline__ void gload_lds16(const unsigned short* g, unsigned short* l) {
    __builtin_amdgcn_global_load_lds((const AS1 unsigned int*)g, (AS3 unsigned int*)l, 16, 0, 0);
}

// ---- gemm1 + fused chunk_sum: one block = one chunk (64 rows x one head's q|k|v).
// Computes qkv panel via MFMA (fp32 inputs reg-staged to bf16 LDS), writes qkvb,
// then reuses the fp32 accumulators to build phi(K)^T / V^T in LDS (unioned with
// dead staging buffers) and runs chunk_sum's 12 MFMAs -> cSf. Grid 1024 = 4/CU.
struct __align__(16) ShQ {
    union {
        struct { unsigned short As[2][64][32]; unsigned short Bs[2][96][32]; } g;  // 20480 B
        struct { unsigned short Kt[DH][VTP]; unsigned short Vt[48][VTP]; } s;      // 11520 B
    };
};

__global__ __launch_bounds__(256) void gemm_qkv_cs(const float* __restrict__ x,
                                                   const float* __restrict__ W,
                                                   unsigned short* __restrict__ qkvb,
                                                   float* __restrict__ cSf)
{
    __shared__ ShQ sh;
    const int tid = threadIdx.x;
    const int lane = tid & 63;
    const int w = tid >> 6;            // wave = 16-row strip
    const int chunk = blockIdx.x;
    const int c = chunk & 31;
    const int h = (chunk >> 5) & 15;
    const int b = chunk >> 9;
    const size_t R0 = (size_t)(b * T_ + c * L_);

    // staging map: thread -> (row sr 0..31, float col sc)
    const int sr = tid >> 3;
    const int sc = (tid & 7) * 4;
    const float* ax  = x + (R0 + sr) * 512 + sc;
    const float* wgq = W + ((size_t)(h * DH) + sr) * 512 + sc;
    const float* wgk = W + ((size_t)(D_ + h * DH) + sr) * 512 + sc;
    const float* wgv = W + ((size_t)(2 * D_ + h * DH) + sr) * 512 + sc;

    f32x4 aL[2], wL[3];
    auto load_stage = [&](int k0) {
        aL[0] = *(const f32x4*)(ax + k0);
        aL[1] = *(const f32x4*)(ax + k0 + (size_t)32 * 512);
        wL[0] = *(const f32x4*)(wgq + k0);
        wL[1] = *(const f32x4*)(wgk + k0);
        wL[2] = *(const f32x4*)(wgv + k0);
    };
    auto cvt4 = [](f32x4 v) {
        u16x4 o;
        o.x = f2bf_rne(v[0]); o.y = f2bf_rne(v[1]);
        o.z = f2bf_rne(v[2]); o.w = f2bf_rne(v[3]);
        return o;
    };
    auto write_stage = [&](int buf) {
        *(u16x4*)&sh.g.As[buf][sr][sc]      = cvt4(aL[0]);
        *(u16x4*)&sh.g.As[buf][sr + 32][sc] = cvt4(aL[1]);
        *(u16x4*)&sh.g.Bs[buf][sr][sc]      = cvt4(wL[0]);
        *(u16x4*)&sh.g.Bs[buf][sr + 32][sc] = cvt4(wL[1]);
        *(u16x4*)&sh.g.Bs[buf][sr + 64][sc] = cvt4(wL[2]);
    };

    f32x4 acc[6];
    #pragma unroll
    for (int n = 0; n < 6; ++n) acc[n] = (f32x4){0.f, 0.f, 0.f, 0.f};

    const int rr = lane & 15;
    const int fg = lane >> 4;
    const int kb = fg * 8;

    load_stage(0);
    write_stage(0);
    __syncthreads();
    int cur = 0;
    for (int k0 = 0; k0 < 512; k0 += 32) {
        const bool more = k0 + 32 < 512;
        if (more) load_stage(k0 + 32);
        bf16x8 af = *(const bf16x8*)&sh.g.As[cur][w * 16 + rr][kb];
        bf16x8 bfr[6];
        #pragma unroll
        for (int n = 0; n < 6; ++n)
            bfr[n] = *(const bf16x8*)&sh.g.Bs[cur][n * 16 + rr][kb];
        #pragma unroll
        for (int n = 0; n < 6; ++n)
            acc[n] = __builtin_amdgcn_mfma_f32_16x16x32_bf16(af, bfr[n], acc[n], 0, 0, 0);
        if (more) write_stage(cur ^ 1);
        __syncthreads();
        cur ^= 1;
    }

    // ---- epilogue A: write qkv panel to global (C/D map: col=rr, row=fg*4+j)
    {
        const int colbase[6] = { h * DH, h * DH + 16,
                                 D_ + h * DH, D_ + h * DH + 16,
                                 2 * D_ + h * DH, 2 * D_ + h * DH + 16 };
        #pragma unroll
        for (int n = 0; n < 6; ++n)
            #pragma unroll
            for (int j = 0; j < 4; ++j) {
                size_t row = R0 + w * 16 + fg * 4 + j;
                qkvb[row * 1536 + colbase[n] + rr] = f2bf(acc[n][j]);
            }
    }

    // ---- epilogue B: transpose phi(K), V into LDS (staging buffers dead after
    // the K-loop's final barrier), then chunk_sum's MFMAs on waves 0..2.
    #pragma unroll
    for (int n = 2; n < 4; ++n)
        #pragma unroll
        for (int j = 0; j < 4; ++j)
            sh.s.Kt[(n - 2) * 16 + rr][w * 16 + fg * 4 + j] = f2bf(phi_s(acc[n][j]));
    #pragma unroll
    for (int n = 4; n < 6; ++n)
        #pragma unroll
        for (int j = 0; j < 4; ++j)
            sh.s.Vt[(n - 4) * 16 + rr][w * 16 + fg * 4 + j] = f2bf(acc[n][j]);
    if (rr == 0) {
        #pragma unroll
        for (int j = 0; j < 4; ++j)
            sh.s.Vt[32][w * 16 + fg * 4 + j] = 0x3F80;   // ones row
    }
    __syncthreads();

    if (w < 3) {    // wave m computes ST rows m*16..m*16+15 (m=2: only e=32 used)
        f32x4 a2[2];
        a2[0] = (f32x4){0.f, 0.f, 0.f, 0.f};
        a2[1] = (f32x4){0.f, 0.f, 0.f, 0.f};
        #pragma unroll
        for (int ks = 0; ks < 2; ++ks) {
            int toff = fg * 8 + ks * 32;
            bf16x8 av = *(const bf16x8*)&sh.s.Vt[w * 16 + rr][toff];
            bf16x8 bkk[2];
            #pragma unroll
            for (int n = 0; n < 2; ++n)
                bkk[n] = *(const bf16x8*)&sh.s.Kt[n * 16 + rr][toff];
            #pragma unroll
            for (int n = 0; n < 2; ++n)
                a2[n] = __builtin_amdgcn_mfma_f32_16x16x32_bf16(av, bkk[n], a2[n], 0, 0, 0);
        }
        float* outp = cSf + (size_t)chunk * CSZ;
        if (w < 2) {
            #pragma unroll
            for (int n = 0; n < 2; ++n)
                #pragma unroll
                for (int r = 0; r < 4; ++r)
                    outp[(w * 16 + fg * 4 + r) * 32 + n * 16 + rr] = a2[n][r];
        } else if (fg == 0) {
            #pragma unroll
            for (int n = 0; n < 2; ++n)
                outp[32 * 32 + n * 16 + rr] = a2[n][0];
        }
    }
}

// ---- gemm2: out = attn @ w_out^T. A bf16 via global_load_lds; W fp32 reg-staged.
template<int BM, bool AF32, bool OUT_BF16>
__global__ __launch_bounds__(256) void gemm_nt(const void* __restrict__ Aptr,
                                               const float* __restrict__ Wf,
                                               void* __restrict__ Cout,
                                               int N, int K)
{
    constexpr int MF = BM / 32;
    constexpr int AF4 = BM / 32;
    __shared__ unsigned short As[2][BM][32];
    __shared__ unsigned short Bs[2][128][32];
    const int tid = threadIdx.x;
    const int lane = tid & 63;
    const int wave = tid >> 6;
    const int wr = wave >> 1;
    const int wc = wave & 1;
    const size_t bm = (size_t)blockIdx.x * BM;
    const size_t bn = (size_t)blockIdx.y * 128;

    const int r8 = lane >> 3;
    const int c4 = (lane & 7) * 4;
    const int lrow = lane >> 2;
    const int lcol = (lane & 3) * 8;

    const float* agf = nullptr;
    const unsigned short* agb = nullptr;
    if constexpr (AF32) agf = (const float*)Aptr + (bm + wave * (BM / 4) + r8) * (size_t)K + c4;
    else                agb = (const unsigned short*)Aptr + (bm + wave * (BM / 4) + lrow) * (size_t)K + lcol;
    const float* wgf = Wf + (bn + wave * 32 + r8) * (size_t)K + c4;

    f32x4 aL[AF4];
    f32x4 wL[4];

    auto load_stage = [&](int buf, int k0) {
        if constexpr (AF32) {
            #pragma unroll
            for (int i = 0; i < AF4; ++i)
                aL[i] = *(const f32x4*)(agf + k0 + (size_t)(i * 8) * K);
        } else {
            gload_lds16(agb + k0, &As[buf][wave * (BM / 4)][0]);
            if constexpr (BM / 4 == 32)
                gload_lds16(agb + (size_t)16 * K + k0, &As[buf][wave * (BM / 4) + 16][0]);
        }
        #pragma unroll
        for (int i = 0; i < 4; ++i)
            wL[i] = *(const f32x4*)(wgf + k0 + (size_t)(i * 8) * K);
    };
    auto write_stage = [&](int buf) {
        if constexpr (AF32) {
            #pragma unroll
            for (int i = 0; i < AF4; ++i) {
                u16x4 o;
                o.x = f2bf_rne(aL[i][0]); o.y = f2bf_rne(aL[i][1]);
                o.z = f2bf_rne(aL[i][2]); o.w = f2bf_rne(aL[i][3]);
                *(u16x4*)&As[buf][wave * (BM / 4) + r8 + i * 8][c4] = o;
            }
        }
        #pragma unroll
        for (int i = 0; i < 4; ++i) {
            u16x4 o;
            o.x = f2bf_rne(wL[i][0]); o.y = f2bf_rne(wL[i][1]);
            o.z = f2bf_rne(wL[i][2]); o.w = f2bf_rne(wL[i][3]);
            *(u16x4*)&Bs[buf][wave * 32 + r8 + i * 8][c4] = o;
        }
    };

    f32x4 acc[MF][4];
    #pragma unroll
    for (int m = 0; m < MF; ++m)
        #pragma unroll
        for (int n = 0; n < 4; ++n)
            acc[m][n] = (f32x4){0.f, 0.f, 0.f, 0.f};

    const int rr = lane & 15;
    const int kb = (lane >> 4) * 8;

    load_stage(0, 0);
    write_stage(0);
    __syncthreads();
    int cur = 0;
    for (int k0 = 0; k0 < K; k0 += 32) {
        const bool more = k0 + 32 < K;
        if (more) load_stage(cur ^ 1, k0 + 32);
        bf16x8 af[MF], bfr[4];
        #pragma unroll
        for (int m = 0; m < MF; ++m)
            af[m] = *(const bf16x8*)&As[cur][wr * (BM / 2) + m * 16 + rr][kb];
        #pragma unroll
        for (int n = 0; n < 4; ++n)
            bfr[n] = *(const bf16x8*)&Bs[cur][wc * 64 + n * 16 + rr][kb];
        #pragma unroll
        for (int m = 0; m < MF; ++m)
            #pragma unroll
            for (int n = 0; n < 4; ++n)
                acc[m][n] = __builtin_amdgcn_mfma_f32_16x16x32_bf16(af[m], bfr[n], acc[m][n], 0, 0, 0);
        if (more) write_stage(cur ^ 1);
        __syncthreads();
        cur ^= 1;
    }

    const int cr = (lane >> 4) * 4;
    const int cc = lane & 15;
    #pragma unroll
    for (int m = 0; m < MF; ++m)
        #pragma unroll
        for (int n = 0; n < 4; ++n)
            #pragma unroll
            for (int j = 0; j < 4; ++j) {
                size_t row = bm + wr * (BM / 2) + m * 16 + cr + j;
                size_t col = bn + wc * 64 + n * 16 + cc;
                float v = acc[m][n][j];
                if (OUT_BF16) ((unsigned short*)Cout)[row * N + col] = f2bf(v);
                else          ((float*)Cout)[row * N + col] = v;
            }
}

// Exclusive prefix over chunks; emit bf16 state cSt[chunk][e*32+d].
__global__ __launch_bounds__(256) void chunk_scan(const float* __restrict__ cSf,
                                                  unsigned short* __restrict__ cSt)
{
    int idx = blockIdx.x * 256 + threadIdx.x;     // 32*1056 = 33792 exactly
    int bh = idx / CSZ;
    int r  = idx % CSZ;
    const float* src = cSf + (size_t)bh * C_ * CSZ + r;
    unsigned short* dst = cSt + (size_t)bh * C_ * CSZ + r;
    float v[C_];
    #pragma unroll
    for (int c = 0; c < C_; ++c) v[c] = src[(size_t)c * CSZ];
    float acc = 0.f;
    #pragma unroll
    for (int c = 0; c < C_; ++c) {
        dst[(size_t)c * CSZ] = f2bf(acc);
        acc += v[c];
    }
}

// Per-chunk output via MFMA. ONE chunk per block; 4 waves, wave w owns m-tile w.
__global__ __launch_bounds__(256) void chunk_out(const unsigned short* __restrict__ qkv,
                                                 const unsigned short* __restrict__ cSt,
                                                 unsigned short* __restrict__ attn)
{
    __shared__ unsigned short Vt[48][VTP];
    __shared__ unsigned short Am[4][16][VTP];
    const int tid = threadIdx.x;
    const int lane = tid & 63;
    const int w = tid >> 6;
    const int chunk = blockIdx.x;
    const int c = chunk & 31;
    const int h = (chunk >> 5) & 15;
    const int b = chunk >> 9;
    const size_t rowbase = ((size_t)(b * T_ + c * L_)) * (3 * D_) + h * DH;
    const int fr = lane & 15;
    const int fg = lane >> 4;

    {
        int t = w * 16 + (lane >> 2);
        int q = lane & 3;
        const unsigned short* vp = qkv + rowbase + (size_t)t * (3 * D_) + 2 * D_ + q * 8;
        bf16x8 v0 = *(const bf16x8*)vp;
        #pragma unroll
        for (int i = 0; i < 8; ++i)
            Vt[q * 8 + i][t] = (unsigned short)v0[i];
        if (q == 0) Vt[32][t] = 0x3F80;
    }

    bf16x8 aq;
    {
        const unsigned short* qp = qkv + rowbase + (size_t)(w * 16 + fr) * (3 * D_) + fg * 8;
        aq = phi_frag(*(const bf16x8*)qp);
    }
    bf16x8 bk[4];
    #pragma unroll
    for (int n = 0; n < 4; ++n) {
        if (n <= w) {
            const unsigned short* kp = qkv + rowbase + (size_t)(n * 16 + fr) * (3 * D_) + D_ + fg * 8;
            bk[n] = phi_frag(*(const bf16x8*)kp);
        }
    }
    bf16x8 bkv[3];
    #pragma unroll
    for (int n = 0; n < 3; ++n)
        bkv[n] = *(const bf16x8*)&cSt[(size_t)chunk * CSZ + (size_t)(n * 16 + fr) * 32 + fg * 8];

    f32x4 zero = (f32x4){0.f, 0.f, 0.f, 0.f};
    f32x4 acc[3];
    #pragma unroll
    for (int n = 0; n < 3; ++n)
        acc[n] = __builtin_amdgcn_mfma_f32_16x16x32_bf16(aq, bkv[n], zero, 0, 0, 0);

    #pragma unroll
    for (int n = 0; n < 4; ++n) {
        if (n <= w) {
            f32x4 s = __builtin_amdgcn_mfma_f32_16x16x32_bf16(aq, bk[n], zero, 0, 0, 0);
            #pragma unroll
            for (int r = 0; r < 4; ++r) {
                unsigned short v = f2bf(s[r]);
                if (n == w && fr > fg * 4 + r) v = 0;
                Am[w][fg * 4 + r][n * 16 + fr] = v;
            }
        }
    }
    if ((w & 1) == 0) {
        int zc = (w + 1) * 16;
        *(uint2*)&Am[w][lane >> 2][zc + (lane & 3) * 4] = (uint2){0u, 0u};
    }
    __syncthreads();

    #pragma unroll
    for (int ks = 0; ks < 2; ++ks) {
        if (ks <= (w >> 1)) {
            bf16x8 bv[3];
            #pragma unroll
            for (int n = 0; n < 3; ++n)
                bv[n] = *(const bf16x8*)&Vt[n * 16 + fr][fg * 8 + ks * 32];
            bf16x8 aa = *(const bf16x8*)&Am[w][fr][fg * 8 + ks * 32];
            #pragma unroll
            for (int n = 0; n < 3; ++n)
                acc[n] = __builtin_amdgcn_mfma_f32_16x16x32_bf16(aa, bv[n], acc[n], 0, 0, 0);
        }
    }

    float dn[4];
    #pragma unroll
    for (int r = 0; r < 4; ++r)
        dn[r] = __shfl(acc[2][r], lane & 48);
    #pragma unroll
    for (int r = 0; r < 4; ++r) {
        float inv = 1.0f / fmaxf(dn[r], 1e-6f);
        #pragma unroll
        for (int n = 0; n < 2; ++n)
            Am[w][fg * 4 + r][n * 16 + fr] = f2bf(acc[n][r] * inv);
    }
    {
        int lrow = lane >> 2;
        int q = lane & 3;
        uint4 o = *(const uint4*)&Am[w][lrow][q * 8];
        size_t grow = (size_t)(b * T_ + c * L_ + w * 16 + lrow);
        *(uint4*)(attn + grow * D_ + h * DH + q * 8) = o;
    }
}

extern "C" void kernel_launch(void* const* d_in, const int* in_sizes, int n_in,
                              void* d_out, int out_size, void* d_ws, size_t ws_size,
                              hipStream_t stream) {
    const float* x     = (const float*)d_in[0];
    const float* w_qkv = (const float*)d_in[1];
    const float* w_out = (const float*)d_in[2];
    float* out = (float*)d_out;

    char* ws = (char*)d_ws;
    unsigned short* qkvb  = (unsigned short*)ws;                 // 12,582,912 B
    unsigned short* attnb = (unsigned short*)(ws + 12582912);    //  4,194,304 B
    float* cSf            = (float*)(ws + 16777216);             //  4,325,376 B  [1024][1056] f32
    unsigned short* cSt   = (unsigned short*)(ws + 21102592);    //  2,162,688 B  [1024][1056] bf16
    // total 23,265,280 B

    // 1) QKV projection + fused per-chunk local sums (1 block = 1 chunk)
    gemm_qkv_cs<<<NC, 256, 0, stream>>>(x, w_qkv, qkvb, cSf);

    // 2) exclusive prefix over chunks
    chunk_scan<<<132, 256, 0, stream>>>(cSf, cSt);

    // 3) per-chunk outputs -> bf16 attn
    chunk_out<<<NC, 256, 0, stream>>>(qkvb, cSt, attnb);

    // 4) output projection: bf16 attn (gload_lds) / fp32 w_out -> fp32 out
    gemm_nt<64, false, false><<<dim3(4096 / 64, 512 / 128), 256, 0, stream>>>(
        attnb, w_out, out, 512, 512);
}